// Round 7
// baseline (1043.363 us; speedup 1.0000x reference)
//
#include <hip/hip_runtime.h>

#define N_NODES 50000
#define N_EDGES 400000
#define EMB 32
#define NREL 8
#define NLAYER 5
#define NPB 16          // nodes per block (half-wave each, 512 threads)
#define KROWS 43        // 0..31 P, 32 Stot, 33..40 S_r, 41 h_dst(rgcnRoot), 42 h_dst(nnRoot)
#define NCHUNK 196      // ceil(50000/256) scan chunks

typedef __attribute__((ext_vector_type(8))) short short8;   // 8 bf16 (4 VGPRs)
typedef __attribute__((ext_vector_type(4))) float f32x4;    // MFMA accumulator

__device__ __forceinline__ unsigned short f2bf(float f) {   // RNE f32 -> bf16
    unsigned u = __float_as_uint(f);
    unsigned r = u + 0x7FFF + ((u >> 16) & 1);
    return (unsigned short)(r >> 16);
}

// ---------------- setup kernels ----------------

__global__ __launch_bounds__(256) void zero_kernel(int* __restrict__ p, int n) {
    int i = blockIdx.x * 256 + threadIdx.x;
    if (i < n) p[i] = 0;
}

__global__ __launch_bounds__(256) void hist_kernel(const int* __restrict__ ei,
                                                   const int* __restrict__ et,
                                                   int* __restrict__ deg,
                                                   int* __restrict__ relcnt) {
    int e = blockIdx.x * 256 + threadIdx.x;
    if (e < N_EDGES) {
        int d = ei[N_EDGES + e];           // dst = edge_index[1]
        atomicAdd(&deg[d], 1);
        atomicAdd(&relcnt[d * NREL + et[e]], 1);
    }
}

// per-chunk sum of deg
__global__ __launch_bounds__(256) void bsum_kernel(const int* __restrict__ deg,
                                                   int* __restrict__ bsum) {
    __shared__ int wsum[4];
    int tid = threadIdx.x, lane = tid & 63, w = tid >> 6;
    int i = blockIdx.x * 256 + tid;
    int v = (i < N_NODES) ? deg[i] : 0;
    #pragma unroll
    for (int off = 32; off > 0; off >>= 1) v += __shfl_down(v, off, 64);
    if (lane == 0) wsum[w] = v;
    __syncthreads();
    if (tid == 0) bsum[blockIdx.x] = wsum[0] + wsum[1] + wsum[2] + wsum[3];
}

// scan chunk sums -> boff; scan degree histogram -> doff; row_ptr[N]=E
__global__ __launch_bounds__(256) void boff_kernel(const int* __restrict__ bsum,
                                                   const int* __restrict__ dcnt,
                                                   int* __restrict__ boff,
                                                   int* __restrict__ doff,
                                                   int* __restrict__ row_ptr) {
    __shared__ int ws[4];
    int tid = threadIdx.x, lane = tid & 63, w = tid >> 6;
    int v = (tid < NCHUNK) ? bsum[tid] : 0;
    int incl = v;
    #pragma unroll
    for (int off = 1; off < 64; off <<= 1) {
        int t = __shfl_up(incl, off, 64);
        if (lane >= off) incl += t;
    }
    if (lane == 63) ws[w] = incl;
    __syncthreads();
    int add = 0;
    for (int j = 0; j < w; j++) add += ws[j];
    if (tid < NCHUNK) boff[tid] = add + incl - v;
    if (tid == 0) row_ptr[N_NODES] = N_EDGES;
    if (w == 0) {   // wave 0 scans the 64-bin degree histogram
        int dv = dcnt[lane];
        int di = dv;
        #pragma unroll
        for (int off = 1; off < 64; off <<= 1) {
            int t = __shfl_up(di, off, 64);
            if (lane >= off) di += t;
        }
        doff[lane] = di - dv;
    }
}

// per-chunk exclusive scan + chunk offset -> row_ptr
__global__ __launch_bounds__(256) void rptr_kernel(const int* __restrict__ deg,
                                                   const int* __restrict__ boff,
                                                   int* __restrict__ row_ptr) {
    __shared__ int ws[4];
    int tid = threadIdx.x, lane = tid & 63, w = tid >> 6;
    int i = blockIdx.x * 256 + tid;
    int v = (i < N_NODES) ? deg[i] : 0;
    int incl = v;
    #pragma unroll
    for (int off = 1; off < 64; off <<= 1) {
        int t = __shfl_up(incl, off, 64);
        if (lane >= off) incl += t;
    }
    if (lane == 63) ws[w] = incl;
    __syncthreads();
    int add = boff[blockIdx.x];
    for (int j = 0; j < w; j++) add += ws[j];
    if (i < N_NODES) row_ptr[i] = add + incl - v;
}

__global__ __launch_bounds__(256) void inv_kernel(const int* __restrict__ deg,
                                                  const int* __restrict__ relcnt,
                                                  float* __restrict__ invdeg,
                                                  float* __restrict__ invcnt,
                                                  int* __restrict__ dcnt) {
    int n = blockIdx.x * 256 + threadIdx.x;
    if (n < N_NODES) {
        int d = deg[n];
        invdeg[n] = 1.0f / (float)(d > 0 ? d : 1);
        atomicAdd(&dcnt[d < 63 ? d : 63], 1);
        #pragma unroll
        for (int r = 0; r < NREL; r++) {
            int c = relcnt[n * NREL + r];
            invcnt[n * NREL + r] = 1.0f / (float)(c > 0 ? c : 1);
        }
    }
}

// counting-sort permutation: perm[pos] = n, nodes ordered by degree class
__global__ __launch_bounds__(256) void perm_kernel(const int* __restrict__ deg,
                                                   const int* __restrict__ doff,
                                                   int* __restrict__ dcur,
                                                   int* __restrict__ perm) {
    int n = blockIdx.x * 256 + threadIdx.x;
    if (n < N_NODES) {
        int d = deg[n];
        d = d < 63 ? d : 63;
        int pos = doff[d] + atomicAdd(&dcur[d], 1);
        perm[pos] = n;
    }
}

__global__ __launch_bounds__(256) void scatter_kernel(const int* __restrict__ ei,
                                                      const int* __restrict__ et,
                                                      const float* __restrict__ ed,
                                                      const int* __restrict__ row_ptr,
                                                      int* __restrict__ cursor,
                                                      int2* __restrict__ edge2) {
    int e = blockIdx.x * 256 + threadIdx.x;
    if (e < N_EDGES) {
        int d = ei[N_EDGES + e];
        int pos = row_ptr[d] + atomicAdd(&cursor[d], 1);
        edge2[pos] = make_int2(ei[e] | (et[e] << 16), __float_as_int(ed[e]));
    }
}

// transpose+bf16 contraction weights: WB[m][o*32+i] = bf16(src_m[i*32+o])
// m 0..31: W2 rows; 32: b2; 33+l*10+j: j<8 rgcnW[l][j], j==8 rgcnRoot[l], j==9 nnRoot[l]
__global__ __launch_bounds__(256) void wtbf_kernel(const float* __restrict__ W2,
                                                   const float* __restrict__ b2,
                                                   const float* __restrict__ rgcnW,
                                                   const float* __restrict__ rgcnRoot,
                                                   const float* __restrict__ nnRoot,
                                                   unsigned short* __restrict__ WB) {
    int m = blockIdx.x;
    const float* src;
    if (m < 32) src = W2 + (size_t)m * 1024;
    else if (m == 32) src = b2;
    else {
        int t = m - 33, l = t / 10, j = t % 10;
        src = (j < 8) ? rgcnW + (size_t)(l * 8 + j) * 1024
            : (j == 8) ? rgcnRoot + (size_t)l * 1024
                       : nnRoot + (size_t)l * 1024;
    }
    unsigned short* dst = WB + (size_t)m * 1024;
    #pragma unroll
    for (int c = 0; c < 4; c++) {
        int idx = c * 256 + threadIdx.x;
        int o = idx >> 5, i = idx & 31;
        dst[o * 32 + i] = f2bf(src[i * 32 + o]);
    }
}

// ---------------- fc: h0 = relu(x @ fc_W + fc_b) ----------------

__global__ __launch_bounds__(256) void fc_kernel(const float* __restrict__ x,
                                                 const float* __restrict__ W,
                                                 const float* __restrict__ b,
                                                 float* __restrict__ h) {
    __shared__ __align__(16) float xt[8][EMB];
    int tid = threadIdx.x;
    int nl = tid >> 5, lane = tid & 31;
    int n0 = blockIdx.x * 8;
    xt[tid >> 5][tid & 31] = x[n0 * EMB + tid];
    __syncthreads();
    float acc = b[lane];
    #pragma unroll
    for (int i = 0; i < EMB; i++) acc += xt[nl][i] * W[i * EMB + lane];
    h[(n0 + nl) * EMB + lane] = fmaxf(acc, 0.0f);
}

// ---------------- fused layer kernel ----------------
// Nodes are processed in degree-sorted order (perm) so all 16 half-waves of a
// block have near-equal trip counts -> minimal barrier imbalance.
// Edge phase (half-wave per node, lane = input feature i):
//   P[k][i] = sum_e hid_e[k]*h[src_e][i];  S_r[i] via ds_add_f32 into Sacc.
// Contraction: C[16,32] = A[16,43x32] x B[43x32,32] via mfma_f32_16x16x32_bf16;
// deterministic cross-wave reduction (RedAll overlay, no atomics).
__global__ __launch_bounds__(512, 2) void layer_kernel(
    const float* __restrict__ h,
    const int2* __restrict__ edge2,
    const int* __restrict__ row_ptr,
    const int* __restrict__ perm,
    const float* __restrict__ invdeg,
    const float* __restrict__ invcnt,
    const float* __restrict__ W1,
    const float* __restrict__ b1,
    const unsigned short* __restrict__ WBs,   // rows 0..32 (W2^T, b2^T)
    const unsigned short* __restrict__ WBl,   // rows 33..42 (rgcnW^T x8, rgcnRoot^T, nnRoot^T)
    const float* __restrict__ rgcnBias_l,
    const float* __restrict__ nnBias_l,
    float* __restrict__ hout)
{
    __shared__ __align__(16) unsigned short P_lds[NPB][KROWS][EMB];  // 44032 B
    __shared__ __align__(16) float hidst[NPB][EMB];                  // 2048 B
    __shared__ __align__(16) float Sacc[NPB][NREL][EMB];             // 16384 B

    const int tid = threadIdx.x;
    const int hw = tid >> 5, lane = tid & 31;
    const int n0 = blockIdx.x * NPB;
    const int n = perm[n0 + hw];              // degree-sorted node id

    // ---------- edge phase (fp32, registers) ----------
    float P[32];
    #pragma unroll
    for (int k = 0; k < 32; k++) P[k] = 0.0f;
    #pragma unroll
    for (int r = 0; r < NREL; r++) Sacc[hw][r][lane] = 0.0f;   // own half-wave only

    const float w10 = W1[lane];
    const float b1v = b1[lane];

    const int pb = row_ptr[n], pe = row_ptr[n + 1];
    if (pb < pe) {
        int2 e0 = edge2[pb];
        int2 e1 = (pb + 1 < pe) ? edge2[pb + 1] : e0;
        float hv0 = h[(e0.x & 0xFFFF) * EMB + lane];
        float hv1 = h[(e1.x & 0xFFFF) * EMB + lane];
        for (int p = pb; p < pe; p++) {
            int p2 = (p + 2 < pe) ? p + 2 : pe - 1;
            int2 e2 = edge2[p2];                              // 2-deep prefetch
            float hv2 = h[(e2.x & 0xFFFF) * EMB + lane];
            int r = (e0.x >> 16) & 7;
            float dist = __int_as_float(e0.y);
            atomicAdd(&Sacc[hw][r][lane], hv0);               // ds_add_f32, no VALU chain
            float hid = fmaxf(fmaf(dist, w10, W1[(1 + r) * EMB + lane] + b1v), 0.0f);
            hidst[hw][lane] = hid;            // half-wave broadcast (same wave, lockstep)
            #pragma unroll
            for (int j = 0; j < 8; j++) {
                float4 h4 = ((const float4*)&hidst[hw][0])[j];
                P[4 * j + 0] = fmaf(h4.x, hv0, P[4 * j + 0]);
                P[4 * j + 1] = fmaf(h4.y, hv0, P[4 * j + 1]);
                P[4 * j + 2] = fmaf(h4.z, hv0, P[4 * j + 2]);
                P[4 * j + 3] = fmaf(h4.w, hv0, P[4 * j + 3]);
            }
            e0 = e1; e1 = e2; hv0 = hv1; hv1 = hv2;
        }
    }
    __threadfence_block();   // drain same-wave ds_add before readback

    // ---------- write bf16 A-rows (pre-scaled) ----------
    const float idg = invdeg[n];
    #pragma unroll
    for (int k = 0; k < 32; k++) P_lds[hw][k][lane] = f2bf(P[k] * idg);
    float S[NREL];
    float stot = 0.0f;
    #pragma unroll
    for (int r = 0; r < NREL; r++) { S[r] = Sacc[hw][r][lane]; stot += S[r]; }
    P_lds[hw][32][lane] = f2bf(stot * idg);
    #pragma unroll
    for (int r = 0; r < NREL; r++)
        P_lds[hw][33 + r][lane] = f2bf(S[r] * invcnt[n * NREL + r]);
    unsigned short hdb = f2bf(h[n * EMB + lane]);
    P_lds[hw][41][lane] = hdb;                // h_dst for rgcnRoot K-step
    P_lds[hw][42][lane] = hdb;                // h_dst for nnRoot K-step
    __syncthreads();

    // ---------- MFMA contraction ----------
    const int wl = tid & 63;                  // wave lane
    const int w = tid >> 6;                   // wave id 0..7
    const int node16 = wl & 15;
    const int quad = wl >> 4;
    const int o0 = wl & 15;                   // B n-index (tile 0); tile 1 = +16

    f32x4 accN0 = {0.f, 0.f, 0.f, 0.f}, accN1 = {0.f, 0.f, 0.f, 0.f};
    f32x4 accR0 = {0.f, 0.f, 0.f, 0.f}, accR1 = {0.f, 0.f, 0.f, 0.f};

    #pragma unroll
    for (int j = 0; j < 6; j++) {
        const int rr = w + 8 * j;             // wave-uniform
        if (rr < KROWS) {
            const unsigned short* Bsrc = (rr < 33) ? (WBs + (size_t)rr * 1024)
                                                   : (WBl + (size_t)(rr - 33) * 1024);
            short8 bf0 = *(const short8*)(Bsrc + o0 * 32 + quad * 8);
            short8 bf1 = *(const short8*)(Bsrc + (o0 + 16) * 32 + quad * 8);
            short8 a = *(const short8*)&P_lds[node16][rr][quad * 8];
            if (rr <= 32 || rr == 42) {
                accN0 = __builtin_amdgcn_mfma_f32_16x16x32_bf16(a, bf0, accN0, 0, 0, 0);
                accN1 = __builtin_amdgcn_mfma_f32_16x16x32_bf16(a, bf1, accN1, 0, 0, 0);
            } else {
                accR0 = __builtin_amdgcn_mfma_f32_16x16x32_bf16(a, bf0, accR0, 0, 0, 0);
                accR1 = __builtin_amdgcn_mfma_f32_16x16x32_bf16(a, bf1, accR1, 0, 0, 0);
            }
        }
    }
    __syncthreads();                          // all A-reads done; safe to overlay RedAll

    // ---------- deterministic cross-wave reduction (no atomics) ----------
    float* RedAll = (float*)&P_lds[0][0][0];  // 8 waves x 1024 floats = 32 KiB < 44 KiB
    {
        float* my = RedAll + w * 1024;
        #pragma unroll
        for (int reg = 0; reg < 4; reg++) {
            int nd = quad * 4 + reg;          // C/D: row(m=node)=quad*4+reg, col(n=o)=lane&15
            my[nd * 32 + o0]            = accN0[reg];
            my[nd * 32 + o0 + 16]       = accN1[reg];
            my[512 + nd * 32 + o0]      = accR0[reg];
            my[512 + nd * 32 + o0 + 16] = accR1[reg];
        }
    }
    __syncthreads();

    // ---------- epilogue (node slot = hw, output col = lane) ----------
    {
        float sn = 0.0f, sr = 0.0f;
        #pragma unroll
        for (int ww = 0; ww < 8; ww++) {
            sn += RedAll[ww * 1024 + tid];          // stride-1, conflict-free
            sr += RedAll[ww * 1024 + 512 + tid];
        }
        float hd = h[n * EMB + lane];
        float o_r = fmaxf(sr + rgcnBias_l[lane], 0.0f);
        float o_n = fmaxf(sn + nnBias_l[lane], 0.0f);
        hout[n * EMB + lane] = hd + o_r + o_n;
    }
}

// ---------------- launch ----------------

extern "C" void kernel_launch(void* const* d_in, const int* in_sizes, int n_in,
                              void* d_out, int out_size, void* d_ws, size_t ws_size,
                              hipStream_t stream) {
    const float* x        = (const float*)d_in[0];
    const int*   ei       = (const int*)d_in[1];
    const int*   et       = (const int*)d_in[2];
    const float* ed       = (const float*)d_in[3];
    const float* fcW      = (const float*)d_in[4];
    const float* fcb      = (const float*)d_in[5];
    const float* rgcnW    = (const float*)d_in[6];
    const float* rgcnRoot = (const float*)d_in[7];
    const float* rgcnBias = (const float*)d_in[8];
    const float* W1       = (const float*)d_in[9];
    const float* b1       = (const float*)d_in[10];
    const float* W2       = (const float*)d_in[11];
    const float* b2       = (const float*)d_in[12];
    const float* nnRoot   = (const float*)d_in[13];
    const float* nnBias   = (const float*)d_in[14];

    float* ws = (float*)d_ws;
    float* h_a    = ws;  ws += (size_t)N_NODES * EMB;
    float* h_b    = ws;  ws += (size_t)N_NODES * EMB;
    float* invdeg = ws;  ws += (size_t)N_NODES;
    float* invcnt = ws;  ws += (size_t)N_NODES * NREL;
    unsigned short* WB = (unsigned short*)ws;  ws += (size_t)83 * 1024 / 2;  // 83 rows bf16
    int2* edge2   = (int2*)ws;     ws += (size_t)N_EDGES * 2;
    int* row_ptr  = (int*)ws;      ws += (size_t)(N_NODES + 1);
    int* perm     = (int*)ws;      ws += (size_t)N_NODES;
    int* bsum     = (int*)ws;      ws += (size_t)NCHUNK;
    int* boff     = (int*)ws;      ws += (size_t)NCHUNK;
    int* doff     = (int*)ws;      ws += (size_t)64;
    int* deg      = (int*)ws;      ws += (size_t)N_NODES;       // deg..dcur contiguous (zeroed)
    int* relcnt   = (int*)ws;      ws += (size_t)N_NODES * NREL;
    int* cursor   = (int*)ws;      ws += (size_t)N_NODES;
    int* dcnt     = (int*)ws;      ws += (size_t)64;
    int* dcur     = (int*)ws;      ws += (size_t)64;
    (void)in_sizes; (void)n_in; (void)out_size; (void)ws_size;

    const int ZN = 10 * N_NODES + 128;
    zero_kernel<<<(ZN + 255) / 256, 256, 0, stream>>>(deg, ZN);
    hist_kernel<<<(N_EDGES + 255) / 256, 256, 0, stream>>>(ei, et, deg, relcnt);
    bsum_kernel<<<NCHUNK, 256, 0, stream>>>(deg, bsum);
    inv_kernel<<<(N_NODES + 255) / 256, 256, 0, stream>>>(deg, relcnt, invdeg, invcnt, dcnt);
    boff_kernel<<<1, 256, 0, stream>>>(bsum, dcnt, boff, doff, row_ptr);
    rptr_kernel<<<NCHUNK, 256, 0, stream>>>(deg, boff, row_ptr);
    perm_kernel<<<(N_NODES + 255) / 256, 256, 0, stream>>>(deg, doff, dcur, perm);
    scatter_kernel<<<(N_EDGES + 255) / 256, 256, 0, stream>>>(ei, et, ed, row_ptr,
                                                              cursor, edge2);
    wtbf_kernel<<<83, 256, 0, stream>>>(W2, b2, rgcnW, rgcnRoot, nnRoot, WB);
    fc_kernel<<<N_NODES / 8, 256, 0, stream>>>(x, fcW, fcb, h_a);

    const float* hin = h_a;
    float* houtb = h_b;
    for (int l = 0; l < NLAYER; l++) {
        float* dst = (l == NLAYER - 1) ? (float*)d_out : houtb;
        layer_kernel<<<N_NODES / NPB, 512, 0, stream>>>(
            hin, edge2, row_ptr, perm, invdeg, invcnt, W1, b1,
            WB, WB + (size_t)(33 + l * 10) * 1024,
            rgcnBias + (size_t)l * EMB,
            nnBias + (size_t)l * EMB,
            dst);
        float* old_in = (float*)hin;
        hin = dst;
        houtb = old_in;
    }
}

// Round 8
// 753.338 us; speedup vs baseline: 1.3850x; 1.3850x over previous
//
#include <hip/hip_runtime.h>

#define N_NODES 50000
#define N_EDGES 400000
#define EMB 32
#define NREL 8
#define NLAYER 5
#define NPB 16          // nodes per block (half-wave each, 512 threads)
#define KROWS 43        // 0..31 P, 32 Stot, 33..40 S_r, 41 h_dst(rgcnRoot), 42 h_dst(nnRoot)
#define NCHUNK 196      // ceil(50000/256) scan chunks

typedef __attribute__((ext_vector_type(8))) short short8;   // 8 bf16 (4 VGPRs)
typedef __attribute__((ext_vector_type(4))) float f32x4;    // MFMA accumulator

__device__ __forceinline__ unsigned short f2bf(float f) {   // RNE f32 -> bf16
    unsigned u = __float_as_uint(f);
    unsigned r = u + 0x7FFF + ((u >> 16) & 1);
    return (unsigned short)(r >> 16);
}

// ---------------- setup kernels ----------------

__global__ __launch_bounds__(256) void zero_kernel(int* __restrict__ p, int n) {
    int i = blockIdx.x * 256 + threadIdx.x;
    if (i < n) p[i] = 0;
}

__global__ __launch_bounds__(256) void hist_kernel(const int* __restrict__ ei,
                                                   const int* __restrict__ et,
                                                   int* __restrict__ deg,
                                                   int* __restrict__ relcnt) {
    int e = blockIdx.x * 256 + threadIdx.x;
    if (e < N_EDGES) {
        int d = ei[N_EDGES + e];           // dst = edge_index[1]
        atomicAdd(&deg[d], 1);
        atomicAdd(&relcnt[d * NREL + et[e]], 1);
    }
}

// per-chunk sum of deg
__global__ __launch_bounds__(256) void bsum_kernel(const int* __restrict__ deg,
                                                   int* __restrict__ bsum) {
    __shared__ int wsum[4];
    int tid = threadIdx.x, lane = tid & 63, w = tid >> 6;
    int i = blockIdx.x * 256 + tid;
    int v = (i < N_NODES) ? deg[i] : 0;
    #pragma unroll
    for (int off = 32; off > 0; off >>= 1) v += __shfl_down(v, off, 64);
    if (lane == 0) wsum[w] = v;
    __syncthreads();
    if (tid == 0) bsum[blockIdx.x] = wsum[0] + wsum[1] + wsum[2] + wsum[3];
}

// scan chunk sums -> boff; scan degree histogram -> doff; row_ptr[N]=E
__global__ __launch_bounds__(256) void boff_kernel(const int* __restrict__ bsum,
                                                   const int* __restrict__ dcnt,
                                                   int* __restrict__ boff,
                                                   int* __restrict__ doff,
                                                   int* __restrict__ row_ptr) {
    __shared__ int ws[4];
    int tid = threadIdx.x, lane = tid & 63, w = tid >> 6;
    int v = (tid < NCHUNK) ? bsum[tid] : 0;
    int incl = v;
    #pragma unroll
    for (int off = 1; off < 64; off <<= 1) {
        int t = __shfl_up(incl, off, 64);
        if (lane >= off) incl += t;
    }
    if (lane == 63) ws[w] = incl;
    __syncthreads();
    int add = 0;
    for (int j = 0; j < w; j++) add += ws[j];
    if (tid < NCHUNK) boff[tid] = add + incl - v;
    if (tid == 0) row_ptr[N_NODES] = N_EDGES;
    if (w == 0) {   // wave 0 scans the 64-bin degree histogram
        int dv = dcnt[lane];
        int di = dv;
        #pragma unroll
        for (int off = 1; off < 64; off <<= 1) {
            int t = __shfl_up(di, off, 64);
            if (lane >= off) di += t;
        }
        doff[lane] = di - dv;
    }
}

// per-chunk exclusive scan + chunk offset -> row_ptr
__global__ __launch_bounds__(256) void rptr_kernel(const int* __restrict__ deg,
                                                   const int* __restrict__ boff,
                                                   int* __restrict__ row_ptr) {
    __shared__ int ws[4];
    int tid = threadIdx.x, lane = tid & 63, w = tid >> 6;
    int i = blockIdx.x * 256 + tid;
    int v = (i < N_NODES) ? deg[i] : 0;
    int incl = v;
    #pragma unroll
    for (int off = 1; off < 64; off <<= 1) {
        int t = __shfl_up(incl, off, 64);
        if (lane >= off) incl += t;
    }
    if (lane == 63) ws[w] = incl;
    __syncthreads();
    int add = boff[blockIdx.x];
    for (int j = 0; j < w; j++) add += ws[j];
    if (i < N_NODES) row_ptr[i] = add + incl - v;
}

// invdeg/invcnt + degree histogram via per-block LDS histogram (low-contention)
__global__ __launch_bounds__(256) void inv_kernel(const int* __restrict__ deg,
                                                  const int* __restrict__ relcnt,
                                                  float* __restrict__ invdeg,
                                                  float* __restrict__ invcnt,
                                                  int* __restrict__ dcnt) {
    __shared__ int lbin[64];
    int tid = threadIdx.x;
    if (tid < 64) lbin[tid] = 0;
    __syncthreads();
    int n = blockIdx.x * 256 + tid;
    if (n < N_NODES) {
        int d = deg[n];
        invdeg[n] = 1.0f / (float)(d > 0 ? d : 1);
        atomicAdd(&lbin[d < 63 ? d : 63], 1);          // LDS atomic
        #pragma unroll
        for (int r = 0; r < NREL; r++) {
            int c = relcnt[n * NREL + r];
            invcnt[n * NREL + r] = 1.0f / (float)(c > 0 ? c : 1);
        }
    }
    __syncthreads();
    if (tid < 64 && lbin[tid] > 0) atomicAdd(&dcnt[tid], lbin[tid]);   // 1 global atomic/bin/block
}

// counting-sort permutation, low-contention: LDS rank + one global reserve per bin
__global__ __launch_bounds__(256) void perm_kernel(const int* __restrict__ deg,
                                                   const int* __restrict__ doff,
                                                   int* __restrict__ dcur,
                                                   int* __restrict__ perm) {
    __shared__ int lbin[64];
    __shared__ int lbase[64];
    int tid = threadIdx.x;
    if (tid < 64) lbin[tid] = 0;
    __syncthreads();
    int n = blockIdx.x * 256 + tid;
    int d = 63, myrank = 0;
    if (n < N_NODES) {
        d = deg[n];
        d = d < 63 ? d : 63;
        myrank = atomicAdd(&lbin[d], 1);               // LDS atomic -> rank in block
    }
    __syncthreads();
    if (tid < 64 && lbin[tid] > 0)
        lbase[tid] = atomicAdd(&dcur[tid], lbin[tid]); // reserve contiguous range
    __syncthreads();
    if (n < N_NODES)
        perm[doff[d] + lbase[d] + myrank] = n;
}

__global__ __launch_bounds__(256) void scatter_kernel(const int* __restrict__ ei,
                                                      const int* __restrict__ et,
                                                      const float* __restrict__ ed,
                                                      const int* __restrict__ row_ptr,
                                                      int* __restrict__ cursor,
                                                      int2* __restrict__ edge2) {
    int e = blockIdx.x * 256 + threadIdx.x;
    if (e < N_EDGES) {
        int d = ei[N_EDGES + e];
        int pos = row_ptr[d] + atomicAdd(&cursor[d], 1);
        edge2[pos] = make_int2(ei[e] | (et[e] << 16), __float_as_int(ed[e]));
    }
}

// transpose+bf16 contraction weights: WB[m][o*32+i] = bf16(src_m[i*32+o])
// m 0..31: W2 rows; 32: b2; 33+l*10+j: j<8 rgcnW[l][j], j==8 rgcnRoot[l], j==9 nnRoot[l]
__global__ __launch_bounds__(256) void wtbf_kernel(const float* __restrict__ W2,
                                                   const float* __restrict__ b2,
                                                   const float* __restrict__ rgcnW,
                                                   const float* __restrict__ rgcnRoot,
                                                   const float* __restrict__ nnRoot,
                                                   unsigned short* __restrict__ WB) {
    int m = blockIdx.x;
    const float* src;
    if (m < 32) src = W2 + (size_t)m * 1024;
    else if (m == 32) src = b2;
    else {
        int t = m - 33, l = t / 10, j = t % 10;
        src = (j < 8) ? rgcnW + (size_t)(l * 8 + j) * 1024
            : (j == 8) ? rgcnRoot + (size_t)l * 1024
                       : nnRoot + (size_t)l * 1024;
    }
    unsigned short* dst = WB + (size_t)m * 1024;
    #pragma unroll
    for (int c = 0; c < 4; c++) {
        int idx = c * 256 + threadIdx.x;
        int o = idx >> 5, i = idx & 31;
        dst[o * 32 + i] = f2bf(src[i * 32 + o]);
    }
}

// ---------------- fc: h0 = relu(x @ fc_W + fc_b) ----------------

__global__ __launch_bounds__(256) void fc_kernel(const float* __restrict__ x,
                                                 const float* __restrict__ W,
                                                 const float* __restrict__ b,
                                                 float* __restrict__ h) {
    __shared__ __align__(16) float xt[8][EMB];
    int tid = threadIdx.x;
    int nl = tid >> 5, lane = tid & 31;
    int n0 = blockIdx.x * 8;
    xt[tid >> 5][tid & 31] = x[n0 * EMB + tid];
    __syncthreads();
    float acc = b[lane];
    #pragma unroll
    for (int i = 0; i < EMB; i++) acc += xt[nl][i] * W[i * EMB + lane];
    h[(n0 + nl) * EMB + lane] = fmaxf(acc, 0.0f);
}

// ---------------- fused layer kernel ----------------
// Nodes processed in degree-sorted order (perm): equal trip counts per block.
// Edge phase (half-wave per node, lane = input feature i):
//   P[k][i] = sum_e hid_e[k]*h[src_e][i];  S_r[i] via ds_add_f32 into Sacc.
// Contraction: C[16,32] = A[16,43x32] x B[43x32,32] via mfma_f32_16x16x32_bf16;
// deterministic cross-wave reduction (RedAll overlay, no atomics).
__global__ __launch_bounds__(512, 2) void layer_kernel(
    const float* __restrict__ h,
    const int2* __restrict__ edge2,
    const int* __restrict__ row_ptr,
    const int* __restrict__ perm,
    const float* __restrict__ invdeg,
    const float* __restrict__ invcnt,
    const float* __restrict__ W1,
    const float* __restrict__ b1,
    const unsigned short* __restrict__ WBs,   // rows 0..32 (W2^T, b2^T)
    const unsigned short* __restrict__ WBl,   // rows 33..42 (rgcnW^T x8, rgcnRoot^T, nnRoot^T)
    const float* __restrict__ rgcnBias_l,
    const float* __restrict__ nnBias_l,
    float* __restrict__ hout)
{
    __shared__ __align__(16) unsigned short P_lds[NPB][KROWS][EMB];  // 44032 B
    __shared__ __align__(16) float hidst[NPB][EMB];                  // 2048 B
    __shared__ __align__(16) float Sacc[NPB][NREL][EMB];             // 16384 B

    const int tid = threadIdx.x;
    const int hw = tid >> 5, lane = tid & 31;
    const int n0 = blockIdx.x * NPB;
    const int n = perm[n0 + hw];              // degree-sorted node id

    // ---------- edge phase (fp32, registers) ----------
    float P[32];
    #pragma unroll
    for (int k = 0; k < 32; k++) P[k] = 0.0f;
    #pragma unroll
    for (int r = 0; r < NREL; r++) Sacc[hw][r][lane] = 0.0f;   // own half-wave only

    const float w10 = W1[lane];
    const float b1v = b1[lane];

    const int pb = row_ptr[n], pe = row_ptr[n + 1];
    if (pb < pe) {
        int2 e0 = edge2[pb];
        int2 e1 = (pb + 1 < pe) ? edge2[pb + 1] : e0;
        float hv0 = h[(e0.x & 0xFFFF) * EMB + lane];
        float hv1 = h[(e1.x & 0xFFFF) * EMB + lane];
        for (int p = pb; p < pe; p++) {
            int p2 = (p + 2 < pe) ? p + 2 : pe - 1;
            int2 e2 = edge2[p2];                              // 2-deep prefetch
            float hv2 = h[(e2.x & 0xFFFF) * EMB + lane];
            int r = (e0.x >> 16) & 7;
            float dist = __int_as_float(e0.y);
            atomicAdd(&Sacc[hw][r][lane], hv0);               // ds_add_f32, no VALU chain
            float hid = fmaxf(fmaf(dist, w10, W1[(1 + r) * EMB + lane] + b1v), 0.0f);
            hidst[hw][lane] = hid;            // half-wave broadcast (same wave, lockstep)
            #pragma unroll
            for (int j = 0; j < 8; j++) {
                float4 h4 = ((const float4*)&hidst[hw][0])[j];
                P[4 * j + 0] = fmaf(h4.x, hv0, P[4 * j + 0]);
                P[4 * j + 1] = fmaf(h4.y, hv0, P[4 * j + 1]);
                P[4 * j + 2] = fmaf(h4.z, hv0, P[4 * j + 2]);
                P[4 * j + 3] = fmaf(h4.w, hv0, P[4 * j + 3]);
            }
            e0 = e1; e1 = e2; hv0 = hv1; hv1 = hv2;
        }
    }
    __threadfence_block();   // drain same-wave ds_add before readback

    // ---------- write bf16 A-rows (pre-scaled) ----------
    const float idg = invdeg[n];
    #pragma unroll
    for (int k = 0; k < 32; k++) P_lds[hw][k][lane] = f2bf(P[k] * idg);
    float S[NREL];
    float stot = 0.0f;
    #pragma unroll
    for (int r = 0; r < NREL; r++) { S[r] = Sacc[hw][r][lane]; stot += S[r]; }
    P_lds[hw][32][lane] = f2bf(stot * idg);
    #pragma unroll
    for (int r = 0; r < NREL; r++)
        P_lds[hw][33 + r][lane] = f2bf(S[r] * invcnt[n * NREL + r]);
    unsigned short hdb = f2bf(h[n * EMB + lane]);
    P_lds[hw][41][lane] = hdb;                // h_dst for rgcnRoot K-step
    P_lds[hw][42][lane] = hdb;                // h_dst for nnRoot K-step
    __syncthreads();

    // ---------- MFMA contraction ----------
    const int wl = tid & 63;                  // wave lane
    const int w = tid >> 6;                   // wave id 0..7
    const int node16 = wl & 15;
    const int quad = wl >> 4;
    const int o0 = wl & 15;                   // B n-index (tile 0); tile 1 = +16

    f32x4 accN0 = {0.f, 0.f, 0.f, 0.f}, accN1 = {0.f, 0.f, 0.f, 0.f};
    f32x4 accR0 = {0.f, 0.f, 0.f, 0.f}, accR1 = {0.f, 0.f, 0.f, 0.f};

    #pragma unroll
    for (int j = 0; j < 6; j++) {
        const int rr = w + 8 * j;             // wave-uniform
        if (rr < KROWS) {
            const unsigned short* Bsrc = (rr < 33) ? (WBs + (size_t)rr * 1024)
                                                   : (WBl + (size_t)(rr - 33) * 1024);
            short8 bf0 = *(const short8*)(Bsrc + o0 * 32 + quad * 8);
            short8 bf1 = *(const short8*)(Bsrc + (o0 + 16) * 32 + quad * 8);
            short8 a = *(const short8*)&P_lds[node16][rr][quad * 8];
            if (rr <= 32 || rr == 42) {
                accN0 = __builtin_amdgcn_mfma_f32_16x16x32_bf16(a, bf0, accN0, 0, 0, 0);
                accN1 = __builtin_amdgcn_mfma_f32_16x16x32_bf16(a, bf1, accN1, 0, 0, 0);
            } else {
                accR0 = __builtin_amdgcn_mfma_f32_16x16x32_bf16(a, bf0, accR0, 0, 0, 0);
                accR1 = __builtin_amdgcn_mfma_f32_16x16x32_bf16(a, bf1, accR1, 0, 0, 0);
            }
        }
    }
    __syncthreads();                          // all A-reads done; safe to overlay RedAll

    // ---------- deterministic cross-wave reduction (no atomics) ----------
    float* RedAll = (float*)&P_lds[0][0][0];  // 8 waves x 1024 floats = 32 KiB < 44 KiB
    {
        float* my = RedAll + w * 1024;
        #pragma unroll
        for (int reg = 0; reg < 4; reg++) {
            int nd = quad * 4 + reg;          // C/D: row(m=node)=quad*4+reg, col(n=o)=lane&15
            my[nd * 32 + o0]            = accN0[reg];
            my[nd * 32 + o0 + 16]       = accN1[reg];
            my[512 + nd * 32 + o0]      = accR0[reg];
            my[512 + nd * 32 + o0 + 16] = accR1[reg];
        }
    }
    __syncthreads();

    // ---------- epilogue (node slot = hw, output col = lane) ----------
    {
        float sn = 0.0f, sr = 0.0f;
        #pragma unroll
        for (int ww = 0; ww < 8; ww++) {
            sn += RedAll[ww * 1024 + tid];          // stride-1, conflict-free
            sr += RedAll[ww * 1024 + 512 + tid];
        }
        float hd = h[n * EMB + lane];
        float o_r = fmaxf(sr + rgcnBias_l[lane], 0.0f);
        float o_n = fmaxf(sn + nnBias_l[lane], 0.0f);
        hout[n * EMB + lane] = hd + o_r + o_n;
    }
}

// ---------------- launch ----------------

extern "C" void kernel_launch(void* const* d_in, const int* in_sizes, int n_in,
                              void* d_out, int out_size, void* d_ws, size_t ws_size,
                              hipStream_t stream) {
    const float* x        = (const float*)d_in[0];
    const int*   ei       = (const int*)d_in[1];
    const int*   et       = (const int*)d_in[2];
    const float* ed       = (const float*)d_in[3];
    const float* fcW      = (const float*)d_in[4];
    const float* fcb      = (const float*)d_in[5];
    const float* rgcnW    = (const float*)d_in[6];
    const float* rgcnRoot = (const float*)d_in[7];
    const float* rgcnBias = (const float*)d_in[8];
    const float* W1       = (const float*)d_in[9];
    const float* b1       = (const float*)d_in[10];
    const float* W2       = (const float*)d_in[11];
    const float* b2       = (const float*)d_in[12];
    const float* nnRoot   = (const float*)d_in[13];
    const float* nnBias   = (const float*)d_in[14];

    float* ws = (float*)d_ws;
    float* h_a    = ws;  ws += (size_t)N_NODES * EMB;
    float* h_b    = ws;  ws += (size_t)N_NODES * EMB;
    float* invdeg = ws;  ws += (size_t)N_NODES;
    float* invcnt = ws;  ws += (size_t)N_NODES * NREL;
    unsigned short* WB = (unsigned short*)ws;  ws += (size_t)83 * 1024 / 2;  // 83 rows bf16
    int2* edge2   = (int2*)ws;     ws += (size_t)N_EDGES * 2;
    int* row_ptr  = (int*)ws;      ws += (size_t)(N_NODES + 1);
    int* perm     = (int*)ws;      ws += (size_t)N_NODES;
    int* bsum     = (int*)ws;      ws += (size_t)NCHUNK;
    int* boff     = (int*)ws;      ws += (size_t)NCHUNK;
    int* doff     = (int*)ws;      ws += (size_t)64;
    int* deg      = (int*)ws;      ws += (size_t)N_NODES;       // deg..dcur contiguous (zeroed)
    int* relcnt   = (int*)ws;      ws += (size_t)N_NODES * NREL;
    int* cursor   = (int*)ws;      ws += (size_t)N_NODES;
    int* dcnt     = (int*)ws;      ws += (size_t)64;
    int* dcur     = (int*)ws;      ws += (size_t)64;
    (void)in_sizes; (void)n_in; (void)out_size; (void)ws_size;

    const int ZN = 10 * N_NODES + 128;
    zero_kernel<<<(ZN + 255) / 256, 256, 0, stream>>>(deg, ZN);
    hist_kernel<<<(N_EDGES + 255) / 256, 256, 0, stream>>>(ei, et, deg, relcnt);
    bsum_kernel<<<NCHUNK, 256, 0, stream>>>(deg, bsum);
    inv_kernel<<<(N_NODES + 255) / 256, 256, 0, stream>>>(deg, relcnt, invdeg, invcnt, dcnt);
    boff_kernel<<<1, 256, 0, stream>>>(bsum, dcnt, boff, doff, row_ptr);
    rptr_kernel<<<NCHUNK, 256, 0, stream>>>(deg, boff, row_ptr);
    perm_kernel<<<(N_NODES + 255) / 256, 256, 0, stream>>>(deg, doff, dcur, perm);
    scatter_kernel<<<(N_EDGES + 255) / 256, 256, 0, stream>>>(ei, et, ed, row_ptr,
                                                              cursor, edge2);
    wtbf_kernel<<<83, 256, 0, stream>>>(W2, b2, rgcnW, rgcnRoot, nnRoot, WB);
    fc_kernel<<<N_NODES / 8, 256, 0, stream>>>(x, fcW, fcb, h_a);

    const float* hin = h_a;
    float* houtb = h_b;
    for (int l = 0; l < NLAYER; l++) {
        float* dst = (l == NLAYER - 1) ? (float*)d_out : houtb;
        layer_kernel<<<N_NODES / NPB, 512, 0, stream>>>(
            hin, edge2, row_ptr, perm, invdeg, invcnt, W1, b1,
            WB, WB + (size_t)(33 + l * 10) * 1024,
            rgcnBias + (size_t)l * EMB,
            nnBias + (size_t)l * EMB,
            dst);
        float* old_in = (float*)hin;
        hin = dst;
        houtb = old_in;
    }
}

// Round 9
// 723.262 us; speedup vs baseline: 1.4426x; 1.0416x over previous
//
#include <hip/hip_runtime.h>

#define N_NODES 50000
#define N_EDGES 400000
#define EMB 32
#define NREL 8
#define NLAYER 5
#define NPB 16          // nodes per block (half-wave each, 512 threads)
#define KROWS 43        // 0..31 P, 32 Stot, 33..40 S_r, 41 h_dst(rgcnRoot), 42 h_dst(nnRoot)
#define NCHUNK 196      // ceil(50000/256) scan chunks

typedef __attribute__((ext_vector_type(8))) short short8;   // 8 bf16 (4 VGPRs)
typedef __attribute__((ext_vector_type(4))) float f32x4;    // MFMA accumulator

__device__ __forceinline__ unsigned short f2bf(float f) {   // RNE f32 -> bf16
    unsigned u = __float_as_uint(f);
    unsigned r = u + 0x7FFF + ((u >> 16) & 1);
    return (unsigned short)(r >> 16);
}

// ---------------- setup kernels ----------------

__global__ __launch_bounds__(256) void zero_kernel(int* __restrict__ p, int n) {
    int i = blockIdx.x * 256 + threadIdx.x;
    if (i < n) p[i] = 0;
}

__global__ __launch_bounds__(256) void hist_kernel(const int* __restrict__ ei,
                                                   const int* __restrict__ et,
                                                   int* __restrict__ deg,
                                                   int* __restrict__ relcnt) {
    int e = blockIdx.x * 256 + threadIdx.x;
    if (e < N_EDGES) {
        int d = ei[N_EDGES + e];           // dst = edge_index[1]
        atomicAdd(&deg[d], 1);
        atomicAdd(&relcnt[d * NREL + et[e]], 1);
    }
}

// per-chunk sum of deg
__global__ __launch_bounds__(256) void bsum_kernel(const int* __restrict__ deg,
                                                   int* __restrict__ bsum) {
    __shared__ int wsum[4];
    int tid = threadIdx.x, lane = tid & 63, w = tid >> 6;
    int i = blockIdx.x * 256 + tid;
    int v = (i < N_NODES) ? deg[i] : 0;
    #pragma unroll
    for (int off = 32; off > 0; off >>= 1) v += __shfl_down(v, off, 64);
    if (lane == 0) wsum[w] = v;
    __syncthreads();
    if (tid == 0) bsum[blockIdx.x] = wsum[0] + wsum[1] + wsum[2] + wsum[3];
}

// scan chunk sums -> boff; scan degree histogram -> doff; row_ptr[N]=E
__global__ __launch_bounds__(256) void boff_kernel(const int* __restrict__ bsum,
                                                   const int* __restrict__ dcnt,
                                                   int* __restrict__ boff,
                                                   int* __restrict__ doff,
                                                   int* __restrict__ row_ptr) {
    __shared__ int ws[4];
    int tid = threadIdx.x, lane = tid & 63, w = tid >> 6;
    int v = (tid < NCHUNK) ? bsum[tid] : 0;
    int incl = v;
    #pragma unroll
    for (int off = 1; off < 64; off <<= 1) {
        int t = __shfl_up(incl, off, 64);
        if (lane >= off) incl += t;
    }
    if (lane == 63) ws[w] = incl;
    __syncthreads();
    int add = 0;
    for (int j = 0; j < w; j++) add += ws[j];
    if (tid < NCHUNK) boff[tid] = add + incl - v;
    if (tid == 0) row_ptr[N_NODES] = N_EDGES;
    if (w == 0) {   // wave 0 scans the 64-bin degree histogram
        int dv = dcnt[lane];
        int di = dv;
        #pragma unroll
        for (int off = 1; off < 64; off <<= 1) {
            int t = __shfl_up(di, off, 64);
            if (lane >= off) di += t;
        }
        doff[lane] = di - dv;
    }
}

// per-chunk exclusive scan + chunk offset -> row_ptr
__global__ __launch_bounds__(256) void rptr_kernel(const int* __restrict__ deg,
                                                   const int* __restrict__ boff,
                                                   int* __restrict__ row_ptr) {
    __shared__ int ws[4];
    int tid = threadIdx.x, lane = tid & 63, w = tid >> 6;
    int i = blockIdx.x * 256 + tid;
    int v = (i < N_NODES) ? deg[i] : 0;
    int incl = v;
    #pragma unroll
    for (int off = 1; off < 64; off <<= 1) {
        int t = __shfl_up(incl, off, 64);
        if (lane >= off) incl += t;
    }
    if (lane == 63) ws[w] = incl;
    __syncthreads();
    int add = boff[blockIdx.x];
    for (int j = 0; j < w; j++) add += ws[j];
    if (i < N_NODES) row_ptr[i] = add + incl - v;
}

// invdeg/invcnt + degree histogram via per-block LDS histogram (low-contention)
__global__ __launch_bounds__(256) void inv_kernel(const int* __restrict__ deg,
                                                  const int* __restrict__ relcnt,
                                                  float* __restrict__ invdeg,
                                                  float* __restrict__ invcnt,
                                                  int* __restrict__ dcnt) {
    __shared__ int lbin[64];
    int tid = threadIdx.x;
    if (tid < 64) lbin[tid] = 0;
    __syncthreads();
    int n = blockIdx.x * 256 + tid;
    if (n < N_NODES) {
        int d = deg[n];
        invdeg[n] = 1.0f / (float)(d > 0 ? d : 1);
        atomicAdd(&lbin[d < 63 ? d : 63], 1);          // LDS atomic
        #pragma unroll
        for (int r = 0; r < NREL; r++) {
            int c = relcnt[n * NREL + r];
            invcnt[n * NREL + r] = 1.0f / (float)(c > 0 ? c : 1);
        }
    }
    __syncthreads();
    if (tid < 64 && lbin[tid] > 0) atomicAdd(&dcnt[tid], lbin[tid]);   // 1 global atomic/bin/block
}

// counting-sort permutation, low-contention: LDS rank + one global reserve per bin
__global__ __launch_bounds__(256) void perm_kernel(const int* __restrict__ deg,
                                                   const int* __restrict__ doff,
                                                   int* __restrict__ dcur,
                                                   int* __restrict__ perm) {
    __shared__ int lbin[64];
    __shared__ int lbase[64];
    int tid = threadIdx.x;
    if (tid < 64) lbin[tid] = 0;
    __syncthreads();
    int n = blockIdx.x * 256 + tid;
    int d = 63, myrank = 0;
    if (n < N_NODES) {
        d = deg[n];
        d = d < 63 ? d : 63;
        myrank = atomicAdd(&lbin[d], 1);               // LDS atomic -> rank in block
    }
    __syncthreads();
    if (tid < 64 && lbin[tid] > 0)
        lbase[tid] = atomicAdd(&dcur[tid], lbin[tid]); // reserve contiguous range
    __syncthreads();
    if (n < N_NODES)
        perm[doff[d] + lbase[d] + myrank] = n;
}

__global__ __launch_bounds__(256) void scatter_kernel(const int* __restrict__ ei,
                                                      const int* __restrict__ et,
                                                      const float* __restrict__ ed,
                                                      const int* __restrict__ row_ptr,
                                                      int* __restrict__ cursor,
                                                      int2* __restrict__ edge2) {
    int e = blockIdx.x * 256 + threadIdx.x;
    if (e < N_EDGES) {
        int d = ei[N_EDGES + e];
        int pos = row_ptr[d] + atomicAdd(&cursor[d], 1);
        edge2[pos] = make_int2(ei[e] | (et[e] << 16), __float_as_int(ed[e]));
    }
}

// transpose+bf16 contraction weights: WB[m][o*32+i] = bf16(src_m[i*32+o])
// m 0..31: W2 rows; 32: b2; 33+l*10+j: j<8 rgcnW[l][j], j==8 rgcnRoot[l], j==9 nnRoot[l]
__global__ __launch_bounds__(256) void wtbf_kernel(const float* __restrict__ W2,
                                                   const float* __restrict__ b2,
                                                   const float* __restrict__ rgcnW,
                                                   const float* __restrict__ rgcnRoot,
                                                   const float* __restrict__ nnRoot,
                                                   unsigned short* __restrict__ WB) {
    int m = blockIdx.x;
    const float* src;
    if (m < 32) src = W2 + (size_t)m * 1024;
    else if (m == 32) src = b2;
    else {
        int t = m - 33, l = t / 10, j = t % 10;
        src = (j < 8) ? rgcnW + (size_t)(l * 8 + j) * 1024
            : (j == 8) ? rgcnRoot + (size_t)l * 1024
                       : nnRoot + (size_t)l * 1024;
    }
    unsigned short* dst = WB + (size_t)m * 1024;
    #pragma unroll
    for (int c = 0; c < 4; c++) {
        int idx = c * 256 + threadIdx.x;
        int o = idx >> 5, i = idx & 31;
        dst[o * 32 + i] = f2bf(src[i * 32 + o]);
    }
}

// ---------------- fc: h0 = relu(x @ fc_W + fc_b) ----------------

__global__ __launch_bounds__(256) void fc_kernel(const float* __restrict__ x,
                                                 const float* __restrict__ W,
                                                 const float* __restrict__ b,
                                                 float* __restrict__ h) {
    __shared__ __align__(16) float xt[8][EMB];
    int tid = threadIdx.x;
    int nl = tid >> 5, lane = tid & 31;
    int n0 = blockIdx.x * 8;
    xt[tid >> 5][tid & 31] = x[n0 * EMB + tid];
    __syncthreads();
    float acc = b[lane];
    #pragma unroll
    for (int i = 0; i < EMB; i++) acc += xt[nl][i] * W[i * EMB + lane];
    h[(n0 + nl) * EMB + lane] = fmaxf(acc, 0.0f);
}

// ---------------- fused layer kernel ----------------
// Nodes processed in degree-sorted order (perm): equal trip counts per block.
// Edge phase (half-wave per node, lane = input feature i):
//   P[k][i] = sum_e hid_e[k]*h[src_e][i];  S_r[i] via ds_add_f32 into an
//   Sacc OVERLAY on the half-wave's own P_lds slice (rows 0..15) — keeps
//   LDS at 46080 B -> 3 blocks/CU (R8's separate 16 KB Sacc cost a block).
// Contraction: C[16,32] = A[16,43x32] x B[43x32,32] via mfma_f32_16x16x32_bf16;
// deterministic cross-wave reduction (RedAll overlay, no atomics).
__global__ __launch_bounds__(512, 2) void layer_kernel(
    const float* __restrict__ h,
    const int2* __restrict__ edge2,
    const int* __restrict__ row_ptr,
    const int* __restrict__ perm,
    const float* __restrict__ invdeg,
    const float* __restrict__ invcnt,
    const float* __restrict__ W1,
    const float* __restrict__ b1,
    const unsigned short* __restrict__ WBs,   // rows 0..32 (W2^T, b2^T)
    const unsigned short* __restrict__ WBl,   // rows 33..42 (rgcnW^T x8, rgcnRoot^T, nnRoot^T)
    const float* __restrict__ rgcnBias_l,
    const float* __restrict__ nnBias_l,
    float* __restrict__ hout)
{
    __shared__ __align__(16) unsigned short P_lds[NPB][KROWS][EMB];  // 44032 B
    __shared__ __align__(16) float hidst[NPB][EMB];                  // 2048 B
    // total 46080 B -> 3 blocks/CU

    const int tid = threadIdx.x;
    const int hw = tid >> 5, lane = tid & 31;
    const int n0 = blockIdx.x * NPB;
    const int n = perm[n0 + hw];              // degree-sorted node id

    // Sacc overlay: first 1024 B (= bf16 rows 0..15) of this half-wave's own
    // P_lds slice, viewed as float[NREL][EMB]. Only the owning half-wave
    // touches it, and the bf16 A-rows are written AFTER S is read back.
    float* Sacc = (float*)&P_lds[hw][0][0];

    // ---------- edge phase (fp32, registers) ----------
    float P[32];
    #pragma unroll
    for (int k = 0; k < 32; k++) P[k] = 0.0f;
    #pragma unroll
    for (int r = 0; r < NREL; r++) Sacc[r * EMB + lane] = 0.0f;

    const float w10 = W1[lane];
    const float b1v = b1[lane];

    const int pb = row_ptr[n], pe = row_ptr[n + 1];
    if (pb < pe) {
        int2 e0 = edge2[pb];
        int2 e1 = (pb + 1 < pe) ? edge2[pb + 1] : e0;
        float hv0 = h[(e0.x & 0xFFFF) * EMB + lane];
        float hv1 = h[(e1.x & 0xFFFF) * EMB + lane];
        for (int p = pb; p < pe; p++) {
            int p2 = (p + 2 < pe) ? p + 2 : pe - 1;
            int2 e2 = edge2[p2];                              // 2-deep prefetch
            float hv2 = h[(e2.x & 0xFFFF) * EMB + lane];
            int r = (e0.x >> 16) & 7;
            float dist = __int_as_float(e0.y);
            atomicAdd(&Sacc[r * EMB + lane], hv0);            // ds_add_f32, no VALU chain
            float hid = fmaxf(fmaf(dist, w10, W1[(1 + r) * EMB + lane] + b1v), 0.0f);
            hidst[hw][lane] = hid;            // half-wave broadcast (same wave, lockstep)
            #pragma unroll
            for (int j = 0; j < 8; j++) {
                float4 h4 = ((const float4*)&hidst[hw][0])[j];
                P[4 * j + 0] = fmaf(h4.x, hv0, P[4 * j + 0]);
                P[4 * j + 1] = fmaf(h4.y, hv0, P[4 * j + 1]);
                P[4 * j + 2] = fmaf(h4.z, hv0, P[4 * j + 2]);
                P[4 * j + 3] = fmaf(h4.w, hv0, P[4 * j + 3]);
            }
            e0 = e1; e1 = e2; hv0 = hv1; hv1 = hv2;
        }
    }
    __threadfence_block();   // drain same-wave ds_add before readback

    // ---------- read S back, then overwrite with bf16 A-rows ----------
    float S[NREL];
    float stot = 0.0f;
    #pragma unroll
    for (int r = 0; r < NREL; r++) { S[r] = Sacc[r * EMB + lane]; stot += S[r]; }
    __syncthreads();   // memory fence: S reads complete before A-row writes (alias safety)

    const float idg = invdeg[n];
    #pragma unroll
    for (int k = 0; k < 32; k++) P_lds[hw][k][lane] = f2bf(P[k] * idg);
    P_lds[hw][32][lane] = f2bf(stot * idg);
    #pragma unroll
    for (int r = 0; r < NREL; r++)
        P_lds[hw][33 + r][lane] = f2bf(S[r] * invcnt[n * NREL + r]);
    unsigned short hdb = f2bf(h[n * EMB + lane]);
    P_lds[hw][41][lane] = hdb;                // h_dst for rgcnRoot K-step
    P_lds[hw][42][lane] = hdb;                // h_dst for nnRoot K-step
    __syncthreads();

    // ---------- MFMA contraction ----------
    const int wl = tid & 63;                  // wave lane
    const int w = tid >> 6;                   // wave id 0..7
    const int node16 = wl & 15;
    const int quad = wl >> 4;
    const int o0 = wl & 15;                   // B n-index (tile 0); tile 1 = +16

    f32x4 accN0 = {0.f, 0.f, 0.f, 0.f}, accN1 = {0.f, 0.f, 0.f, 0.f};
    f32x4 accR0 = {0.f, 0.f, 0.f, 0.f}, accR1 = {0.f, 0.f, 0.f, 0.f};

    #pragma unroll
    for (int j = 0; j < 6; j++) {
        const int rr = w + 8 * j;             // wave-uniform
        if (rr < KROWS) {
            const unsigned short* Bsrc = (rr < 33) ? (WBs + (size_t)rr * 1024)
                                                   : (WBl + (size_t)(rr - 33) * 1024);
            short8 bf0 = *(const short8*)(Bsrc + o0 * 32 + quad * 8);
            short8 bf1 = *(const short8*)(Bsrc + (o0 + 16) * 32 + quad * 8);
            short8 a = *(const short8*)&P_lds[node16][rr][quad * 8];
            if (rr <= 32 || rr == 42) {
                accN0 = __builtin_amdgcn_mfma_f32_16x16x32_bf16(a, bf0, accN0, 0, 0, 0);
                accN1 = __builtin_amdgcn_mfma_f32_16x16x32_bf16(a, bf1, accN1, 0, 0, 0);
            } else {
                accR0 = __builtin_amdgcn_mfma_f32_16x16x32_bf16(a, bf0, accR0, 0, 0, 0);
                accR1 = __builtin_amdgcn_mfma_f32_16x16x32_bf16(a, bf1, accR1, 0, 0, 0);
            }
        }
    }
    __syncthreads();                          // all A-reads done; safe to overlay RedAll

    // ---------- deterministic cross-wave reduction (no atomics) ----------
    float* RedAll = (float*)&P_lds[0][0][0];  // 8 waves x 1024 floats = 32 KiB < 44 KiB
    {
        float* my = RedAll + w * 1024;
        #pragma unroll
        for (int reg = 0; reg < 4; reg++) {
            int nd = quad * 4 + reg;          // C/D: row(m=node)=quad*4+reg, col(n=o)=lane&15
            my[nd * 32 + o0]            = accN0[reg];
            my[nd * 32 + o0 + 16]       = accN1[reg];
            my[512 + nd * 32 + o0]      = accR0[reg];
            my[512 + nd * 32 + o0 + 16] = accR1[reg];
        }
    }
    __syncthreads();

    // ---------- epilogue (node slot = hw, output col = lane) ----------
    {
        float sn = 0.0f, sr = 0.0f;
        #pragma unroll
        for (int ww = 0; ww < 8; ww++) {
            sn += RedAll[ww * 1024 + tid];          // stride-1, conflict-free
            sr += RedAll[ww * 1024 + 512 + tid];
        }
        float hd = h[n * EMB + lane];
        float o_r = fmaxf(sr + rgcnBias_l[lane], 0.0f);
        float o_n = fmaxf(sn + nnBias_l[lane], 0.0f);
        hout[n * EMB + lane] = hd + o_r + o_n;
    }
}

// ---------------- launch ----------------

extern "C" void kernel_launch(void* const* d_in, const int* in_sizes, int n_in,
                              void* d_out, int out_size, void* d_ws, size_t ws_size,
                              hipStream_t stream) {
    const float* x        = (const float*)d_in[0];
    const int*   ei       = (const int*)d_in[1];
    const int*   et       = (const int*)d_in[2];
    const float* ed       = (const float*)d_in[3];
    const float* fcW      = (const float*)d_in[4];
    const float* fcb      = (const float*)d_in[5];
    const float* rgcnW    = (const float*)d_in[6];
    const float* rgcnRoot = (const float*)d_in[7];
    const float* rgcnBias = (const float*)d_in[8];
    const float* W1       = (const float*)d_in[9];
    const float* b1       = (const float*)d_in[10];
    const float* W2       = (const float*)d_in[11];
    const float* b2       = (const float*)d_in[12];
    const float* nnRoot   = (const float*)d_in[13];
    const float* nnBias   = (const float*)d_in[14];

    float* ws = (float*)d_ws;
    float* h_a    = ws;  ws += (size_t)N_NODES * EMB;
    float* h_b    = ws;  ws += (size_t)N_NODES * EMB;
    float* invdeg = ws;  ws += (size_t)N_NODES;
    float* invcnt = ws;  ws += (size_t)N_NODES * NREL;
    unsigned short* WB = (unsigned short*)ws;  ws += (size_t)83 * 1024 / 2;  // 83 rows bf16
    int2* edge2   = (int2*)ws;     ws += (size_t)N_EDGES * 2;
    int* row_ptr  = (int*)ws;      ws += (size_t)(N_NODES + 1);
    int* perm     = (int*)ws;      ws += (size_t)N_NODES;
    int* bsum     = (int*)ws;      ws += (size_t)NCHUNK;
    int* boff     = (int*)ws;      ws += (size_t)NCHUNK;
    int* doff     = (int*)ws;      ws += (size_t)64;
    int* deg      = (int*)ws;      ws += (size_t)N_NODES;       // deg..dcur contiguous (zeroed)
    int* relcnt   = (int*)ws;      ws += (size_t)N_NODES * NREL;
    int* cursor   = (int*)ws;      ws += (size_t)N_NODES;
    int* dcnt     = (int*)ws;      ws += (size_t)64;
    int* dcur     = (int*)ws;      ws += (size_t)64;
    (void)in_sizes; (void)n_in; (void)out_size; (void)ws_size;

    const int ZN = 10 * N_NODES + 128;
    zero_kernel<<<(ZN + 255) / 256, 256, 0, stream>>>(deg, ZN);
    hist_kernel<<<(N_EDGES + 255) / 256, 256, 0, stream>>>(ei, et, deg, relcnt);
    bsum_kernel<<<NCHUNK, 256, 0, stream>>>(deg, bsum);
    inv_kernel<<<(N_NODES + 255) / 256, 256, 0, stream>>>(deg, relcnt, invdeg, invcnt, dcnt);
    boff_kernel<<<1, 256, 0, stream>>>(bsum, dcnt, boff, doff, row_ptr);
    rptr_kernel<<<NCHUNK, 256, 0, stream>>>(deg, boff, row_ptr);
    perm_kernel<<<(N_NODES + 255) / 256, 256, 0, stream>>>(deg, doff, dcur, perm);
    scatter_kernel<<<(N_EDGES + 255) / 256, 256, 0, stream>>>(ei, et, ed, row_ptr,
                                                              cursor, edge2);
    wtbf_kernel<<<83, 256, 0, stream>>>(W2, b2, rgcnW, rgcnRoot, nnRoot, WB);
    fc_kernel<<<N_NODES / 8, 256, 0, stream>>>(x, fcW, fcb, h_a);

    const float* hin = h_a;
    float* houtb = h_b;
    for (int l = 0; l < NLAYER; l++) {
        float* dst = (l == NLAYER - 1) ? (float*)d_out : houtb;
        layer_kernel<<<N_NODES / NPB, 512, 0, stream>>>(
            hin, edge2, row_ptr, perm, invdeg, invcnt, W1, b1,
            WB, WB + (size_t)(33 + l * 10) * 1024,
            rgcnBias + (size_t)l * EMB,
            nnBias + (size_t)l * EMB,
            dst);
        float* old_in = (float*)hin;
        hin = dst;
        houtb = old_in;
    }
}

// Round 10
// 466.012 us; speedup vs baseline: 2.2389x; 1.5520x over previous
//
#include <hip/hip_runtime.h>

#define N_NODES 50000
#define N_EDGES 400000
#define EMB 32
#define NREL 8
#define NLAYER 5
#define NPB 16          // nodes per block (half-wave each, 512 threads)
#define KROWS 43        // 0..31 P, 32 Stot, 33..40 S_r, 41 h_dst(rgcnRoot), 42 h_dst(nnRoot)
#define NCHUNK 196      // ceil(50000/256) scan chunks

typedef __attribute__((ext_vector_type(8))) short short8;   // 8 bf16 (4 VGPRs)
typedef __attribute__((ext_vector_type(4))) float f32x4;    // MFMA accumulator

__device__ __forceinline__ unsigned short f2bf(float f) {   // RNE f32 -> bf16
    unsigned u = __float_as_uint(f);
    unsigned r = u + 0x7FFF + ((u >> 16) & 1);
    return (unsigned short)(r >> 16);
}

// ---------------- setup kernels ----------------

__global__ __launch_bounds__(256) void zero_kernel(int* __restrict__ p, int n) {
    int i = blockIdx.x * 256 + threadIdx.x;
    if (i < n) p[i] = 0;
}

__global__ __launch_bounds__(256) void hist_kernel(const int* __restrict__ ei,
                                                   const int* __restrict__ et,
                                                   int* __restrict__ deg,
                                                   int* __restrict__ relcnt) {
    int e = blockIdx.x * 256 + threadIdx.x;
    if (e < N_EDGES) {
        int d = ei[N_EDGES + e];           // dst = edge_index[1]
        atomicAdd(&deg[d], 1);
        atomicAdd(&relcnt[d * NREL + et[e]], 1);
    }
}

// per-chunk sum of deg
__global__ __launch_bounds__(256) void bsum_kernel(const int* __restrict__ deg,
                                                   int* __restrict__ bsum) {
    __shared__ int wsum[4];
    int tid = threadIdx.x, lane = tid & 63, w = tid >> 6;
    int i = blockIdx.x * 256 + tid;
    int v = (i < N_NODES) ? deg[i] : 0;
    #pragma unroll
    for (int off = 32; off > 0; off >>= 1) v += __shfl_down(v, off, 64);
    if (lane == 0) wsum[w] = v;
    __syncthreads();
    if (tid == 0) bsum[blockIdx.x] = wsum[0] + wsum[1] + wsum[2] + wsum[3];
}

// scan chunk sums -> boff; row_ptr[N]=E
__global__ __launch_bounds__(256) void boff_kernel(const int* __restrict__ bsum,
                                                   int* __restrict__ boff,
                                                   int* __restrict__ row_ptr) {
    __shared__ int ws[4];
    int tid = threadIdx.x, lane = tid & 63, w = tid >> 6;
    int v = (tid < NCHUNK) ? bsum[tid] : 0;
    int incl = v;
    #pragma unroll
    for (int off = 1; off < 64; off <<= 1) {
        int t = __shfl_up(incl, off, 64);
        if (lane >= off) incl += t;
    }
    if (lane == 63) ws[w] = incl;
    __syncthreads();
    int add = 0;
    for (int j = 0; j < w; j++) add += ws[j];
    if (tid < NCHUNK) boff[tid] = add + incl - v;
    if (tid == 0) row_ptr[N_NODES] = N_EDGES;
}

// per-chunk exclusive scan + chunk offset -> row_ptr
__global__ __launch_bounds__(256) void rptr_kernel(const int* __restrict__ deg,
                                                   const int* __restrict__ boff,
                                                   int* __restrict__ row_ptr) {
    __shared__ int ws[4];
    int tid = threadIdx.x, lane = tid & 63, w = tid >> 6;
    int i = blockIdx.x * 256 + tid;
    int v = (i < N_NODES) ? deg[i] : 0;
    int incl = v;
    #pragma unroll
    for (int off = 1; off < 64; off <<= 1) {
        int t = __shfl_up(incl, off, 64);
        if (lane >= off) incl += t;
    }
    if (lane == 63) ws[w] = incl;
    __syncthreads();
    int add = boff[blockIdx.x];
    for (int j = 0; j < w; j++) add += ws[j];
    if (i < N_NODES) row_ptr[i] = add + incl - v;
}

__global__ __launch_bounds__(256) void inv_kernel(const int* __restrict__ deg,
                                                  const int* __restrict__ relcnt,
                                                  float* __restrict__ invdeg,
                                                  float* __restrict__ invcnt) {
    int n = blockIdx.x * 256 + threadIdx.x;
    if (n < N_NODES) {
        int d = deg[n];
        invdeg[n] = 1.0f / (float)(d > 0 ? d : 1);
        #pragma unroll
        for (int r = 0; r < NREL; r++) {
            int c = relcnt[n * NREL + r];
            invcnt[n * NREL + r] = 1.0f / (float)(c > 0 ? c : 1);
        }
    }
}

__global__ __launch_bounds__(256) void scatter_kernel(const int* __restrict__ ei,
                                                      const int* __restrict__ et,
                                                      const float* __restrict__ ed,
                                                      const int* __restrict__ row_ptr,
                                                      int* __restrict__ cursor,
                                                      int2* __restrict__ edge2) {
    int e = blockIdx.x * 256 + threadIdx.x;
    if (e < N_EDGES) {
        int d = ei[N_EDGES + e];
        int pos = row_ptr[d] + atomicAdd(&cursor[d], 1);
        edge2[pos] = make_int2(ei[e] | (et[e] << 16), __float_as_int(ed[e]));
    }
}

// transpose+bf16 contraction weights: WB[m][o*32+i] = bf16(src_m[i*32+o])
// m 0..31: W2 rows; 32: b2; 33+l*10+j: j<8 rgcnW[l][j], j==8 rgcnRoot[l], j==9 nnRoot[l]
__global__ __launch_bounds__(256) void wtbf_kernel(const float* __restrict__ W2,
                                                   const float* __restrict__ b2,
                                                   const float* __restrict__ rgcnW,
                                                   const float* __restrict__ rgcnRoot,
                                                   const float* __restrict__ nnRoot,
                                                   unsigned short* __restrict__ WB) {
    int m = blockIdx.x;
    const float* src;
    if (m < 32) src = W2 + (size_t)m * 1024;
    else if (m == 32) src = b2;
    else {
        int t = m - 33, l = t / 10, j = t % 10;
        src = (j < 8) ? rgcnW + (size_t)(l * 8 + j) * 1024
            : (j == 8) ? rgcnRoot + (size_t)l * 1024
                       : nnRoot + (size_t)l * 1024;
    }
    unsigned short* dst = WB + (size_t)m * 1024;
    #pragma unroll
    for (int c = 0; c < 4; c++) {
        int idx = c * 256 + threadIdx.x;
        int o = idx >> 5, i = idx & 31;
        dst[o * 32 + i] = f2bf(src[i * 32 + o]);
    }
}

// ---------------- fc: h0 = relu(x @ fc_W + fc_b) ----------------

__global__ __launch_bounds__(256) void fc_kernel(const float* __restrict__ x,
                                                 const float* __restrict__ W,
                                                 const float* __restrict__ b,
                                                 float* __restrict__ h) {
    __shared__ __align__(16) float xt[8][EMB];
    int tid = threadIdx.x;
    int nl = tid >> 5, lane = tid & 31;
    int n0 = blockIdx.x * 8;
    xt[tid >> 5][tid & 31] = x[n0 * EMB + tid];
    __syncthreads();
    float acc = b[lane];
    #pragma unroll
    for (int i = 0; i < EMB; i++) acc += xt[nl][i] * W[i * EMB + lane];
    h[(n0 + nl) * EMB + lane] = fmaxf(acc, 0.0f);
}

// ---------------- fused layer kernel (R6 edge loop + MFMA contraction) ----------------
// Consecutive node mapping (no perm — R9 showed perm costs ~2x via locality
// loss + dispatch-tail imbalance). Edge phase (half-wave per node, lane = i):
//   P[k][i] = sum_e hid_e[k]*h[src_e][i];  S_r[i] in registers (cmp-select chain).
// Contraction: C[16,32] = A[16,43x32] x B[43x32,32] via mfma_f32_16x16x32_bf16;
// deterministic cross-wave reduction (RedAll overlay, no atomics).
__global__ __launch_bounds__(512, 2) void layer_kernel(
    const float* __restrict__ h,
    const int2* __restrict__ edge2,
    const int* __restrict__ row_ptr,
    const float* __restrict__ invdeg,
    const float* __restrict__ invcnt,
    const float* __restrict__ W1,
    const float* __restrict__ b1,
    const unsigned short* __restrict__ WBs,   // rows 0..32 (W2^T, b2^T)
    const unsigned short* __restrict__ WBl,   // rows 33..42 (rgcnW^T x8, rgcnRoot^T, nnRoot^T)
    const float* __restrict__ rgcnBias_l,
    const float* __restrict__ nnBias_l,
    float* __restrict__ hout)
{
    __shared__ __align__(16) unsigned short P_lds[NPB][KROWS][EMB];  // 44032 B
    __shared__ __align__(16) float hidst[NPB][EMB];                  // 2048 B
    // total 46080 B -> 3 blocks/CU

    const int tid = threadIdx.x;
    const int hw = tid >> 5, lane = tid & 31;
    const int n0 = blockIdx.x * NPB;
    const int n = n0 + hw;                    // N divisible by 16: no guard

    // ---------- edge phase (fp32, registers — R6-exact) ----------
    float P[32], S[NREL];
    #pragma unroll
    for (int k = 0; k < 32; k++) P[k] = 0.0f;
    #pragma unroll
    for (int r = 0; r < NREL; r++) S[r] = 0.0f;

    const float w10 = W1[lane];
    const float b1v = b1[lane];

    const int pb = row_ptr[n], pe = row_ptr[n + 1];
    if (pb < pe) {
        int2 e0 = edge2[pb];
        float hv0 = h[(e0.x & 0xFFFF) * EMB + lane];
        for (int p = pb; p < pe; p++) {
            int pn = (p + 1 < pe) ? (p + 1) : (pe - 1);
            int2 e1 = edge2[pn];                              // prefetch
            float hv1 = h[(e1.x & 0xFFFF) * EMB + lane];      // prefetch gather
            int r = (e0.x >> 16) & 7;
            float dist = __int_as_float(e0.y);
            float hid = fmaxf(fmaf(dist, w10, W1[(1 + r) * EMB + lane] + b1v), 0.0f);
            hidst[hw][lane] = hid;            // half-wave broadcast (same wave, lockstep)
            #pragma unroll
            for (int j = 0; j < 8; j++) {
                float4 h4 = ((const float4*)&hidst[hw][0])[j];
                P[4 * j + 0] = fmaf(h4.x, hv0, P[4 * j + 0]);
                P[4 * j + 1] = fmaf(h4.y, hv0, P[4 * j + 1]);
                P[4 * j + 2] = fmaf(h4.z, hv0, P[4 * j + 2]);
                P[4 * j + 3] = fmaf(h4.w, hv0, P[4 * j + 3]);
            }
            #pragma unroll
            for (int rr = 0; rr < NREL; rr++)
                S[rr] += (r == rr) ? hv0 : 0.0f;
            e0 = e1; hv0 = hv1;
        }
    }

    // ---------- write bf16 A-rows (pre-scaled) ----------
    const float idg = invdeg[n];
    #pragma unroll
    for (int k = 0; k < 32; k++) P_lds[hw][k][lane] = f2bf(P[k] * idg);
    float stot = 0.0f;
    #pragma unroll
    for (int r = 0; r < NREL; r++) stot += S[r];
    P_lds[hw][32][lane] = f2bf(stot * idg);
    #pragma unroll
    for (int r = 0; r < NREL; r++)
        P_lds[hw][33 + r][lane] = f2bf(S[r] * invcnt[n * NREL + r]);
    unsigned short hdb = f2bf(h[n * EMB + lane]);
    P_lds[hw][41][lane] = hdb;                // h_dst for rgcnRoot K-step
    P_lds[hw][42][lane] = hdb;                // h_dst for nnRoot K-step
    __syncthreads();

    // ---------- MFMA contraction ----------
    const int wl = tid & 63;                  // wave lane
    const int w = tid >> 6;                   // wave id 0..7
    const int node16 = wl & 15;
    const int quad = wl >> 4;
    const int o0 = wl & 15;                   // B n-index (tile 0); tile 1 = +16

    f32x4 accN0 = {0.f, 0.f, 0.f, 0.f}, accN1 = {0.f, 0.f, 0.f, 0.f};
    f32x4 accR0 = {0.f, 0.f, 0.f, 0.f}, accR1 = {0.f, 0.f, 0.f, 0.f};

    #pragma unroll
    for (int j = 0; j < 6; j++) {
        const int rr = w + 8 * j;             // wave-uniform
        if (rr < KROWS) {
            const unsigned short* Bsrc = (rr < 33) ? (WBs + (size_t)rr * 1024)
                                                   : (WBl + (size_t)(rr - 33) * 1024);
            short8 bf0 = *(const short8*)(Bsrc + o0 * 32 + quad * 8);
            short8 bf1 = *(const short8*)(Bsrc + (o0 + 16) * 32 + quad * 8);
            short8 a = *(const short8*)&P_lds[node16][rr][quad * 8];
            if (rr <= 32 || rr == 42) {
                accN0 = __builtin_amdgcn_mfma_f32_16x16x32_bf16(a, bf0, accN0, 0, 0, 0);
                accN1 = __builtin_amdgcn_mfma_f32_16x16x32_bf16(a, bf1, accN1, 0, 0, 0);
            } else {
                accR0 = __builtin_amdgcn_mfma_f32_16x16x32_bf16(a, bf0, accR0, 0, 0, 0);
                accR1 = __builtin_amdgcn_mfma_f32_16x16x32_bf16(a, bf1, accR1, 0, 0, 0);
            }
        }
    }
    __syncthreads();                          // all A-reads done; safe to overlay RedAll

    // ---------- deterministic cross-wave reduction (no atomics) ----------
    float* RedAll = (float*)&P_lds[0][0][0];  // 8 waves x 1024 floats = 32 KiB < 44 KiB
    {
        float* my = RedAll + w * 1024;
        #pragma unroll
        for (int reg = 0; reg < 4; reg++) {
            int nd = quad * 4 + reg;          // C/D: row(m=node)=quad*4+reg, col(n=o)=lane&15
            my[nd * 32 + o0]            = accN0[reg];
            my[nd * 32 + o0 + 16]       = accN1[reg];
            my[512 + nd * 32 + o0]      = accR0[reg];
            my[512 + nd * 32 + o0 + 16] = accR1[reg];
        }
    }
    __syncthreads();

    // ---------- epilogue (node slot = hw, output col = lane) ----------
    {
        float sn = 0.0f, sr = 0.0f;
        #pragma unroll
        for (int ww = 0; ww < 8; ww++) {
            sn += RedAll[ww * 1024 + tid];          // stride-1, conflict-free
            sr += RedAll[ww * 1024 + 512 + tid];
        }
        float hd = h[n * EMB + lane];
        float o_r = fmaxf(sr + rgcnBias_l[lane], 0.0f);
        float o_n = fmaxf(sn + nnBias_l[lane], 0.0f);
        hout[n * EMB + lane] = hd + o_r + o_n;
    }
}

// ---------------- launch ----------------

extern "C" void kernel_launch(void* const* d_in, const int* in_sizes, int n_in,
                              void* d_out, int out_size, void* d_ws, size_t ws_size,
                              hipStream_t stream) {
    const float* x        = (const float*)d_in[0];
    const int*   ei       = (const int*)d_in[1];
    const int*   et       = (const int*)d_in[2];
    const float* ed       = (const float*)d_in[3];
    const float* fcW      = (const float*)d_in[4];
    const float* fcb      = (const float*)d_in[5];
    const float* rgcnW    = (const float*)d_in[6];
    const float* rgcnRoot = (const float*)d_in[7];
    const float* rgcnBias = (const float*)d_in[8];
    const float* W1       = (const float*)d_in[9];
    const float* b1       = (const float*)d_in[10];
    const float* W2       = (const float*)d_in[11];
    const float* b2       = (const float*)d_in[12];
    const float* nnRoot   = (const float*)d_in[13];
    const float* nnBias   = (const float*)d_in[14];

    float* ws = (float*)d_ws;
    float* h_a    = ws;  ws += (size_t)N_NODES * EMB;
    float* h_b    = ws;  ws += (size_t)N_NODES * EMB;
    float* invdeg = ws;  ws += (size_t)N_NODES;
    float* invcnt = ws;  ws += (size_t)N_NODES * NREL;
    unsigned short* WB = (unsigned short*)ws;  ws += (size_t)83 * 1024 / 2;  // 83 rows bf16
    int2* edge2   = (int2*)ws;     ws += (size_t)N_EDGES * 2;
    int* row_ptr  = (int*)ws;      ws += (size_t)(N_NODES + 1);
    int* bsum     = (int*)ws;      ws += (size_t)NCHUNK;
    int* boff     = (int*)ws;      ws += (size_t)NCHUNK;
    int* deg      = (int*)ws;      ws += (size_t)N_NODES;       // deg..cursor contiguous (zeroed)
    int* relcnt   = (int*)ws;      ws += (size_t)N_NODES * NREL;
    int* cursor   = (int*)ws;      ws += (size_t)N_NODES;
    (void)in_sizes; (void)n_in; (void)out_size; (void)ws_size;

    zero_kernel<<<(10 * N_NODES + 255) / 256, 256, 0, stream>>>(deg, 10 * N_NODES);
    hist_kernel<<<(N_EDGES + 255) / 256, 256, 0, stream>>>(ei, et, deg, relcnt);
    bsum_kernel<<<NCHUNK, 256, 0, stream>>>(deg, bsum);
    inv_kernel<<<(N_NODES + 255) / 256, 256, 0, stream>>>(deg, relcnt, invdeg, invcnt);
    boff_kernel<<<1, 256, 0, stream>>>(bsum, boff, row_ptr);
    rptr_kernel<<<NCHUNK, 256, 0, stream>>>(deg, boff, row_ptr);
    scatter_kernel<<<(N_EDGES + 255) / 256, 256, 0, stream>>>(ei, et, ed, row_ptr,
                                                              cursor, edge2);
    wtbf_kernel<<<83, 256, 0, stream>>>(W2, b2, rgcnW, rgcnRoot, nnRoot, WB);
    fc_kernel<<<N_NODES / 8, 256, 0, stream>>>(x, fcW, fcb, h_a);

    const float* hin = h_a;
    float* houtb = h_b;
    for (int l = 0; l < NLAYER; l++) {
        float* dst = (l == NLAYER - 1) ? (float*)d_out : houtb;
        layer_kernel<<<N_NODES / NPB, 512, 0, stream>>>(
            hin, edge2, row_ptr, invdeg, invcnt, W1, b1,
            WB, WB + (size_t)(33 + l * 10) * 1024,
            rgcnBias + (size_t)l * EMB,
            nnBias + (size_t)l * EMB,
            dst);
        float* old_in = (float*)hin;
        hin = dst;
        houtb = old_in;
    }
}